// Round 1
// baseline (418.219 us; speedup 1.0000x reference)
//
#include <hip/hip_runtime.h>
#include <math.h>

#define T_LEN 65536
#define TPB 256
#define NVEC (T_LEN / 4)     // 16384 float4 per row
#define EPS 1e-8f

__device__ __forceinline__ int sgn_of(float v) {
    return (v > 0.f) - (v < 0.f);
}

__global__ __launch_bounds__(TPB) void stat_feat_kernel(const float* __restrict__ x,
                                                        float* __restrict__ out) {
    const int row = blockIdx.x;                    // 0 .. B*C-1
    const float* __restrict__ xr = x + (size_t)row * T_LEN;
    const float4* __restrict__ xv = (const float4*)xr;
    const int tid = threadIdx.x;
    const int wave = tid >> 6;
    const int lane = tid & 63;

    // ---------------- pass 1: raw moments + extrema + zero-cross ----------------
    float s1 = 0.f, s2 = 0.f, s3 = 0.f, s4 = 0.f, sabs = 0.f, ssqrt = 0.f;
    float mx = -__builtin_inff(), mn = __builtin_inff();
    int zc = 0;

    for (int i = tid; i < NVEC; i += TPB) {
        float4 v = xv[i];
        // previous element (last elem of preceding vector); for i==0 duplicate v.x
        float prev = (i > 0) ? xr[4 * i - 1] : v.x;
        float e[4] = {v.x, v.y, v.z, v.w};
#pragma unroll
        for (int j = 0; j < 4; j++) {
            float t = e[j];
            float t2 = t * t;
            s1 += t;
            s2 += t2;
            s3 = fmaf(t2, t, s3);
            s4 = fmaf(t2, t2, s4);
            float a = fabsf(t);
            sabs += a;
            ssqrt += sqrtf(a);
            mx = fmaxf(mx, t);
            mn = fminf(mn, t);
        }
        int sp = sgn_of(prev);
#pragma unroll
        for (int j = 0; j < 4; j++) {
            int sc = sgn_of(e[j]);
            zc += (sc != sp);
            sp = sc;
        }
    }

    // wave-level reduce (64 lanes)
#pragma unroll
    for (int o = 32; o > 0; o >>= 1) {
        s1 += __shfl_down(s1, o);
        s2 += __shfl_down(s2, o);
        s3 += __shfl_down(s3, o);
        s4 += __shfl_down(s4, o);
        sabs += __shfl_down(sabs, o);
        ssqrt += __shfl_down(ssqrt, o);
        zc += __shfl_down(zc, o);
        mx = fmaxf(mx, __shfl_down(mx, o));
        mn = fminf(mn, __shfl_down(mn, o));
    }

    __shared__ float ls1[4], ls2[4], ls3[4], ls4[4], lsa[4], lss[4], lmx[4], lmn[4];
    __shared__ int lzc[4];
    __shared__ float s_mean;

    if (lane == 0) {
        ls1[wave] = s1; ls2[wave] = s2; ls3[wave] = s3; ls4[wave] = s4;
        lsa[wave] = sabs; lss[wave] = ssqrt; lmx[wave] = mx; lmn[wave] = mn;
        lzc[wave] = zc;
    }
    __syncthreads();

    // thread 0 keeps the totals in registers across pass 2
    float S1 = 0.f, S2 = 0.f, S3 = 0.f, S4 = 0.f, SA = 0.f, SS = 0.f;
    float MX = 0.f, MN = 0.f;
    int ZC = 0;
    if (tid == 0) {
        S1 = ls1[0] + ls1[1] + ls1[2] + ls1[3];
        S2 = ls2[0] + ls2[1] + ls2[2] + ls2[3];
        S3 = ls3[0] + ls3[1] + ls3[2] + ls3[3];
        S4 = ls4[0] + ls4[1] + ls4[2] + ls4[3];
        SA = lsa[0] + lsa[1] + lsa[2] + lsa[3];
        SS = lss[0] + lss[1] + lss[2] + lss[3];
        MX = fmaxf(fmaxf(lmx[0], lmx[1]), fmaxf(lmx[2], lmx[3]));
        MN = fminf(fminf(lmn[0], lmn[1]), fminf(lmn[2], lmn[3]));
        ZC = lzc[0] + lzc[1] + lzc[2] + lzc[3];
        s_mean = S1 / (float)T_LEN;
    }
    __syncthreads();

    // ---------------- pass 2: mean-crossing rate ----------------
    const float m = s_mean;
    int mc = 0;
    for (int i = tid; i < NVEC; i += TPB) {
        float4 v = xv[i];
        float prev = (i > 0) ? xr[4 * i - 1] : v.x;
        float e[4] = {v.x - m, v.y - m, v.z - m, v.w - m};
        int sp = sgn_of(prev - m);
#pragma unroll
        for (int j = 0; j < 4; j++) {
            int sc = sgn_of(e[j]);
            mc += (sc != sp);
            sp = sc;
        }
    }
#pragma unroll
    for (int o = 32; o > 0; o >>= 1) mc += __shfl_down(mc, o);
    __syncthreads();                 // protect LDS reuse ordering
    if (lane == 0) lzc[wave] = mc;
    __syncthreads();

    // ---------------- finalize (thread 0) ----------------
    if (tid == 0) {
        int MC = lzc[0] + lzc[1] + lzc[2] + lzc[3];
        const float Tf = (float)T_LEN;
        float mean = S1 / Tf;
        float sq_mean = S2 / Tf;
        float var = (S2 - S1 * S1 / Tf) / (Tf - 1.f);
        var = fmaxf(var, 0.f);
        float stdv = sqrtf(var);
        float rms = sqrtf(sq_mean);
        float peak = MX;
        float peak_neg = MN;
        float ptp = peak - peak_neg;
        float abs_peak = fabsf(peak);
        float crest = abs_peak / (rms + EPS);
        float mean_abs = SA / Tf;
        float shape = rms / (mean_abs + EPS);
        float impulse = abs_peak / (mean_abs + EPS);
        float sqrt_mean = SS / Tf;
        float clearance = abs_peak / (sqrt_mean * sqrt_mean + EPS);
        float ex3 = S3 / Tf;
        float m3 = ex3 - 3.f * mean * sq_mean + 2.f * mean * mean * mean;
        float m4 = S4 / Tf - 4.f * mean * ex3 + 6.f * mean * mean * sq_mean
                   - 3.f * mean * mean * mean * mean;
        float skew = m3 / (stdv * stdv * stdv + EPS);
        float kurt = m4 / (stdv * stdv * stdv * stdv + EPS) - 3.f;
        float zcr = (float)ZC / (Tf - 1.f);
        float mcr = (float)MC / (Tf - 1.f);
        float margin = abs_peak / (sqrt_mean + EPS);
        float energy = S2;

        float* o = out + (size_t)row * 17;
        o[0] = mean;      o[1] = stdv;     o[2] = var;      o[3] = rms;
        o[4] = peak;      o[5] = peak_neg; o[6] = ptp;      o[7] = crest;
        o[8] = shape;     o[9] = impulse;  o[10] = clearance; o[11] = skew;
        o[12] = kurt;     o[13] = zcr;     o[14] = mcr;     o[15] = margin;
        o[16] = energy;
    }
}

extern "C" void kernel_launch(void* const* d_in, const int* in_sizes, int n_in,
                              void* d_out, int out_size, void* d_ws, size_t ws_size,
                              hipStream_t stream) {
    const float* x = (const float*)d_in[0];
    float* out = (float*)d_out;
    const int rows = in_sizes[0] / T_LEN;   // 64*16 = 1024
    stat_feat_kernel<<<dim3(rows), dim3(TPB), 0, stream>>>(x, out);
}

// Round 2
// 417.420 us; speedup vs baseline: 1.0019x; 1.0019x over previous
//
#include <hip/hip_runtime.h>
#include <math.h>

#define T_LEN      65536
#define TPB        256
#define CHUNKS     8
#define CHUNK_VECS (T_LEN / 4 / CHUNKS)   // 2048 float4 per chunk
#define ITERS      (CHUNK_VECS / TPB)     // 8 float4 per thread
#define EPS        1e-8f

// ------------------------------------------------------------------
// K1: per-(row,chunk) partials: s1,s2,s3,s4,sum|x|,sum sqrt|x|,max,min,zc
// partial arrays are chunk-major: arr[chunk*rows + row]  (coalesced in K2)
// ------------------------------------------------------------------
__global__ __launch_bounds__(TPB) void k1_partials(const float* __restrict__ x,
                                                   float* __restrict__ part,
                                                   int rows) {
    const int blk   = blockIdx.x;
    const int row   = blk >> 3;          // / CHUNKS
    const int chunk = blk & 7;           // % CHUNKS
    const int tid   = threadIdx.x;
    const int lane  = tid & 63;
    const int wave  = tid >> 6;

    const float*  __restrict__ xr = x + (size_t)row * T_LEN;
    const float4* __restrict__ xv = (const float4*)xr;
    const int vbase = chunk * CHUNK_VECS;

    float s1 = 0.f, s2 = 0.f, s3 = 0.f, s4 = 0.f, sa = 0.f, ss = 0.f;
    float mx = -__builtin_inff(), mn = __builtin_inff();
    int zc = 0;

    for (int it = 0; it < ITERS; ++it) {
        const int vi = vbase + it * TPB + tid;     // vector index within row
        float4 v = xv[vi];
        // previous element = v.w of lane-1's vector; lane 0 falls back to a
        // scalar load (1 per wave per iter instead of 1 per thread per iter)
        float prev = __shfl_up(v.w, 1);
        if (lane == 0) prev = (vi > 0) ? xr[4 * vi - 1] : v.x;

        // sign-bit crossings (exact for nonzero samples; zeros measure-zero)
        bool sp = prev < 0.f;
        bool b0 = v.x < 0.f, b1 = v.y < 0.f, b2 = v.z < 0.f, b3 = v.w < 0.f;
        zc += (int)(sp != b0) + (int)(b0 != b1) + (int)(b1 != b2) + (int)(b2 != b3);

        float e[4] = {v.x, v.y, v.z, v.w};
#pragma unroll
        for (int j = 0; j < 4; j++) {
            float t = e[j];
            float t2 = t * t;
            s1 += t;
            s2 = fmaf(t, t, s2);
            s3 = fmaf(t2, t, s3);
            s4 = fmaf(t2, t2, s4);
            float a = fabsf(t);
            sa += a;
            ss += sqrtf(a);
            mx = fmaxf(mx, t);
            mn = fminf(mn, t);
        }
    }

    // wave reduce
#pragma unroll
    for (int o = 32; o > 0; o >>= 1) {
        s1 += __shfl_down(s1, o);
        s2 += __shfl_down(s2, o);
        s3 += __shfl_down(s3, o);
        s4 += __shfl_down(s4, o);
        sa += __shfl_down(sa, o);
        ss += __shfl_down(ss, o);
        zc += __shfl_down(zc, o);
        mx = fmaxf(mx, __shfl_down(mx, o));
        mn = fminf(mn, __shfl_down(mn, o));
    }

    __shared__ float l[9][4];
    if (lane == 0) {
        l[0][wave] = s1; l[1][wave] = s2; l[2][wave] = s3; l[3][wave] = s4;
        l[4][wave] = sa; l[5][wave] = ss; l[6][wave] = mx; l[7][wave] = mn;
        l[8][wave] = (float)zc;
    }
    __syncthreads();
    if (tid == 0) {
        const int N = rows * CHUNKS;
        const int idx = chunk * rows + row;
        part[0 * N + idx] = l[0][0] + l[0][1] + l[0][2] + l[0][3];
        part[1 * N + idx] = l[1][0] + l[1][1] + l[1][2] + l[1][3];
        part[2 * N + idx] = l[2][0] + l[2][1] + l[2][2] + l[2][3];
        part[3 * N + idx] = l[3][0] + l[3][1] + l[3][2] + l[3][3];
        part[4 * N + idx] = l[4][0] + l[4][1] + l[4][2] + l[4][3];
        part[5 * N + idx] = l[5][0] + l[5][1] + l[5][2] + l[5][3];
        part[6 * N + idx] = fmaxf(fmaxf(l[6][0], l[6][1]), fmaxf(l[6][2], l[6][3]));
        part[7 * N + idx] = fminf(fminf(l[7][0], l[7][1]), fminf(l[7][2], l[7][3]));
        part[8 * N + idx] = l[8][0] + l[8][1] + l[8][2] + l[8][3];
    }
}

// ------------------------------------------------------------------
// K2: one thread per row — reduce 8 chunk-partials, write 16 features + mean
// ------------------------------------------------------------------
__global__ __launch_bounds__(TPB) void k2_finalize(const float* __restrict__ part,
                                                   float* __restrict__ meanbuf,
                                                   float* __restrict__ out,
                                                   int rows) {
    const int r = blockIdx.x * TPB + threadIdx.x;
    if (r >= rows) return;
    const int N = rows * CHUNKS;

    float S1 = 0.f, S2 = 0.f, S3 = 0.f, S4 = 0.f, SA = 0.f, SS = 0.f, ZC = 0.f;
    float MX = -__builtin_inff(), MN = __builtin_inff();
#pragma unroll
    for (int c = 0; c < CHUNKS; c++) {
        const int idx = c * rows + r;
        S1 += part[0 * N + idx];
        S2 += part[1 * N + idx];
        S3 += part[2 * N + idx];
        S4 += part[3 * N + idx];
        SA += part[4 * N + idx];
        SS += part[5 * N + idx];
        MX = fmaxf(MX, part[6 * N + idx]);
        MN = fminf(MN, part[7 * N + idx]);
        ZC += part[8 * N + idx];
    }

    const float Tf = (float)T_LEN;
    float mean = S1 / Tf;
    float sq_mean = S2 / Tf;
    float var = (S2 - S1 * S1 / Tf) / (Tf - 1.f);
    var = fmaxf(var, 0.f);
    float stdv = sqrtf(var);
    float rms = sqrtf(sq_mean);
    float peak = MX, peak_neg = MN;
    float ptp = peak - peak_neg;
    float abs_peak = fabsf(peak);
    float crest = abs_peak / (rms + EPS);
    float mean_abs = SA / Tf;
    float shape = rms / (mean_abs + EPS);
    float impulse = abs_peak / (mean_abs + EPS);
    float sqrt_mean = SS / Tf;
    float clearance = abs_peak / (sqrt_mean * sqrt_mean + EPS);
    float ex3 = S3 / Tf;
    float m3 = ex3 - 3.f * mean * sq_mean + 2.f * mean * mean * mean;
    float m4 = S4 / Tf - 4.f * mean * ex3 + 6.f * mean * mean * sq_mean
               - 3.f * mean * mean * mean * mean;
    float skew = m3 / (stdv * stdv * stdv + EPS);
    float kurt = m4 / (stdv * stdv * stdv * stdv + EPS) - 3.f;
    float zcr = ZC / (Tf - 1.f);
    float margin = abs_peak / (sqrt_mean + EPS);

    meanbuf[r] = mean;

    float* o = out + (size_t)r * 17;
    o[0] = mean;   o[1] = stdv;     o[2] = var;       o[3] = rms;
    o[4] = peak;   o[5] = peak_neg; o[6] = ptp;       o[7] = crest;
    o[8] = shape;  o[9] = impulse;  o[10] = clearance; o[11] = skew;
    o[12] = kurt;  o[13] = zcr;     /* o[14]=mcr in K4 */ o[15] = margin;
    o[16] = S2;
}

// ------------------------------------------------------------------
// K3: per-(row,chunk) mean-crossing partial counts
// ------------------------------------------------------------------
__global__ __launch_bounds__(TPB) void k3_mc(const float* __restrict__ x,
                                             const float* __restrict__ meanbuf,
                                             float* __restrict__ mcp,
                                             int rows) {
    const int blk   = blockIdx.x;
    const int row   = blk >> 3;
    const int chunk = blk & 7;
    const int tid   = threadIdx.x;
    const int lane  = tid & 63;
    const int wave  = tid >> 6;

    const float*  __restrict__ xr = x + (size_t)row * T_LEN;
    const float4* __restrict__ xv = (const float4*)xr;
    const float m = meanbuf[row];
    const int vbase = chunk * CHUNK_VECS;

    int mc = 0;
    for (int it = 0; it < ITERS; ++it) {
        const int vi = vbase + it * TPB + tid;
        float4 v = xv[vi];
        float prev = __shfl_up(v.w, 1);
        if (lane == 0) prev = (vi > 0) ? xr[4 * vi - 1] : v.x;
        // crossings of level m == sign changes of (x - m), no subtraction needed
        bool sp = prev < m;
        bool b0 = v.x < m, b1 = v.y < m, b2 = v.z < m, b3 = v.w < m;
        mc += (int)(sp != b0) + (int)(b0 != b1) + (int)(b1 != b2) + (int)(b2 != b3);
    }
#pragma unroll
    for (int o = 32; o > 0; o >>= 1) mc += __shfl_down(mc, o);

    __shared__ int l[4];
    if (lane == 0) l[wave] = mc;
    __syncthreads();
    if (tid == 0)
        mcp[chunk * rows + row] = (float)(l[0] + l[1] + l[2] + l[3]);
}

// ------------------------------------------------------------------
// K4: one thread per row — finalize mcr
// ------------------------------------------------------------------
__global__ __launch_bounds__(TPB) void k4_mcr(const float* __restrict__ mcp,
                                              float* __restrict__ out,
                                              int rows) {
    const int r = blockIdx.x * TPB + threadIdx.x;
    if (r >= rows) return;
    float MC = 0.f;
#pragma unroll
    for (int c = 0; c < CHUNKS; c++) MC += mcp[c * rows + r];
    out[(size_t)r * 17 + 14] = MC / ((float)T_LEN - 1.f);
}

extern "C" void kernel_launch(void* const* d_in, const int* in_sizes, int n_in,
                              void* d_out, int out_size, void* d_ws, size_t ws_size,
                              hipStream_t stream) {
    const float* x = (const float*)d_in[0];
    float* out = (float*)d_out;
    const int rows = in_sizes[0] / T_LEN;    // 1024
    const int N = rows * CHUNKS;             // 8192

    float* ws = (float*)d_ws;
    float* part    = ws;              // 9 * N floats
    float* meanbuf = ws + 9 * N;      // rows floats
    float* mcp     = meanbuf + rows;  // N floats

    k1_partials<<<dim3(N), dim3(TPB), 0, stream>>>(x, part, rows);
    k2_finalize<<<dim3((rows + TPB - 1) / TPB), dim3(TPB), 0, stream>>>(part, meanbuf, out, rows);
    k3_mc<<<dim3(N), dim3(TPB), 0, stream>>>(x, meanbuf, mcp, rows);
    k4_mcr<<<dim3((rows + TPB - 1) / TPB), dim3(TPB), 0, stream>>>(mcp, out, rows);
}